// Round 2
// 78.070 us; speedup vs baseline: 1.0398x; 1.0398x over previous
//
#include <hip/hip_runtime.h>
#include <math.h>

#define NG 1024
#define NC 2
#define HH 224
#define WW 224
#define TILES_X 28
#define TILES_Y 28
#define EPS2D 0.3f
#define ALPHA_MIN (1.0f/255.0f)
#define ALPHA_MAX 0.999f
#define MAXL 512   // per-tile list capacity (worst observed ~250 incl. superset inflation)
#define LOG2E 1.4426950408889634f

// Single dispatch, zero cross-block deps. Per 8x8-pixel tile block:
//  1) conservative prefilter of all 1024 gaussians (superset of exact support)
//  2) compact (z_bits<<10)|gid keys into LDS (keys carry full stable order)
//  3) RANK SORT: each thread holds its <=2 keys in regs, counts smaller keys
//     via broadcast LDS reads (no barriers in loop), scatters keys[rank]=key
//     in place. Identical order to bitonic (keys unique), 45 barriers -> 2.
//  4) full prep in REGISTERS for listed gaussians + EXACT re-cull:
//     alpha>1/255 support bbox is hx=sqrt(2*tau*a), hy=sqrt(2*tau*d) with
//     (a,d) the exact 2D cov diagonal (+EPS2D); entries whose exact bbox
//     misses the tile contribute exactly 0 in the reference. Ballot-based
//     order-preserving compaction writes survivors to sorted slots.
//  5) 4 depth-segment waves composite (conic pre-scaled by 0.5*log2e ->
//     exp2) + associative (C,T) merge.
__global__ __launch_bounds__(256) void fused_kernel(
        const float* __restrict__ w2cs, const float* __restrict__ Ks,
        const float* __restrict__ xyz, const float* __restrict__ rgb,
        const float* __restrict__ opac, const float* __restrict__ scale,
        const float* __restrict__ rot, float* __restrict__ out) {
    const int cam = blockIdx.z;
    const int TX = blockIdx.x, TY = blockIdx.y;
    const int tid = threadIdx.x;
    const int lane = tid & 63;
    const int wv   = tid >> 6;

    // keys and part are never live simultaneously: keys last read in phase 4
    // prep (before its barrier), part first written after the composite loop.
    __shared__ union {
        unsigned long long keys[MAXL];   // 4096 B
        float4 part[4][64];              // 4096 B
    } shu;
    __shared__ float4 sA[MAXL];          // u, v, ia*0.5*log2e, ib*log2e
    __shared__ float4 sB[MAXL];          // id*0.5*log2e, o, r, g
    __shared__ float  sC[MAXL];          // b (blue)
    __shared__ int    cnt[8];
    __shared__ int    scnt;

    if (tid == 0) scnt = 0;
    __syncthreads();

    const float* vm = w2cs + cam*16;
    const float R00 = vm[0],  R01 = vm[1],  R02 = vm[2],  t0 = vm[3];
    const float R10 = vm[4],  R11 = vm[5],  R12 = vm[6],  t1 = vm[7];
    const float R20 = vm[8],  R21 = vm[9],  R22 = vm[10], t2 = vm[11];
    const float* Kc = Ks + cam*9;
    const float fx = Kc[0], cx = Kc[2], fy = Kc[4], cy = Kc[5];
    const float limx = 1.3f * (0.5f * (float)WW / fx);
    const float limy = 1.3f * (0.5f * (float)HH / fy);

    // ---- phase 1: conservative prefilter, 4 gaussians per thread ----
    #pragma unroll
    for (int k = 0; k < 4; k++) {
        int g = k*256 + tid;
        float X = xyz[g*3], Y = xyz[g*3+1], Z = xyz[g*3+2];
        float pz = R20*X + R21*Y + R22*Z + t2;
        float o  = opac[g];
        float tau = __logf(255.f * o);
        bool cand = (pz > 0.01f) && (pz < 100.f) && (tau > 0.f);
        if (cand) {
            float rz = 1.f / pz;
            float px = R00*X + R01*Y + R02*Z + t0;
            float py = R10*X + R11*Y + R12*Z + t1;
            float uu = fx*px*rz + cx;
            float vv = fy*py*rz + cy;
            float sx = scale[g*3+0], sy = scale[g*3+1], sz = scale[g*3+2];
            float smax = fmaxf(sx, fmaxf(sy, sz));
            float j00 = fx*rz, j11 = fy*rz;
            float j02m = fx*limx*rz, j12m = fy*limy*rz;   // |j02| bound via |tx|<=limx*z
            float abnd = smax*smax*(j00*j00 + j02m*j02m) + EPS2D;  // >= exact a
            float dbnd = smax*smax*(j11*j11 + j12m*j12m) + EPS2D;  // >= exact d
            float rx = sqrtf(2.f*tau*abnd) + 0.01f;
            float ry = sqrtf(2.f*tau*dbnd) + 0.01f;
            int xmin = max((int)ceilf (uu - rx - 0.5f), 0);
            int xmax = min((int)floorf(uu + rx - 0.5f), WW-1);
            int ymin = max((int)ceilf (vv - ry - 0.5f), 0);
            int ymax = min((int)floorf(vv + ry - 0.5f), HH-1);
            cand = (xmin <= xmax) && (ymin <= ymax) &&
                   (TX >= (xmin>>3)) && (TX <= (xmax>>3)) &&
                   (TY >= (ymin>>3)) && (TY <= (ymax>>3));
        }
        unsigned long long m = __ballot(cand);
        int cw = __popcll(m);
        if (cw) {
            int basepos = 0;
            if (lane == 0) basepos = atomicAdd(&scnt, cw);
            basepos = __shfl(basepos, 0);
            if (cand) {
                int pos = basepos + __popcll(m & ((1ull << lane) - 1ull));
                if (pos < MAXL)
                    shu.keys[pos] = ((unsigned long long)__float_as_uint(pz) << 10)
                                  | (unsigned long long)g;
            }
        }
    }
    __syncthreads();
    int n = min(scnt, MAXL);

    // ---- phase 2: rank sort (barrier-free counting; keys unique via gid) ----
    unsigned long long myk0 = (tid       < n) ? shu.keys[tid]       : 0ull;
    unsigned long long myk1 = (tid + 256 < n) ? shu.keys[tid + 256] : 0ull;
    int r0 = 0, r1 = 0;
    #pragma unroll 4
    for (int j = 0; j < n; j++) {
        unsigned long long kj = shu.keys[j];   // wave-uniform -> LDS broadcast
        r0 += (kj < myk0) ? 1 : 0;
        r1 += (kj < myk1) ? 1 : 0;
    }
    __syncthreads();                 // all reads done before in-place scatter
    if (tid       < n) shu.keys[r0] = myk0;
    if (tid + 256 < n) shu.keys[r1] = myk1;
    __syncthreads();

    // ---- phase 3: prep in registers + exact-bbox re-cull ----
    auto prep = [&](int i, float4 &A, float4 &B, float &C) -> bool {
        if (i >= n) return false;
        int g = (int)(shu.keys[i] & 1023ull);

        float qw = rot[g*4+0], qx = rot[g*4+1], qy = rot[g*4+2], qz = rot[g*4+3];
        float qn = rsqrtf(qw*qw + qx*qx + qy*qy + qz*qz);
        qw *= qn; qx *= qn; qy *= qn; qz *= qn;
        float r00 = 1.f - 2.f*(qy*qy + qz*qz), r01 = 2.f*(qx*qy - qw*qz), r02 = 2.f*(qx*qz + qw*qy);
        float r10 = 2.f*(qx*qy + qw*qz), r11 = 1.f - 2.f*(qx*qx + qz*qz), r12 = 2.f*(qy*qz - qw*qx);
        float r20 = 2.f*(qx*qz - qw*qy), r21 = 2.f*(qy*qz + qw*qx), r22 = 1.f - 2.f*(qx*qx + qy*qy);

        float sx = scale[g*3+0], sy = scale[g*3+1], sz = scale[g*3+2];
        float m00 = r00*sx, m01 = r01*sy, m02 = r02*sz;
        float m10 = r10*sx, m11 = r11*sy, m12 = r12*sz;
        float m20 = r20*sx, m21 = r21*sy, m22 = r22*sz;
        float c00 = m00*m00 + m01*m01 + m02*m02;
        float c01 = m00*m10 + m01*m11 + m02*m12;
        float c02 = m00*m20 + m01*m21 + m02*m22;
        float c11 = m10*m10 + m11*m11 + m12*m12;
        float c12 = m10*m20 + m11*m21 + m12*m22;
        float c22 = m20*m20 + m21*m21 + m22*m22;

        float X = xyz[g*3], Y = xyz[g*3+1], Z = xyz[g*3+2];
        float px = R00*X + R01*Y + R02*Z + t0;
        float py = R10*X + R11*Y + R12*Z + t1;
        float pz = R20*X + R21*Y + R22*Z + t2;
        float rz = 1.f / pz;

        float txc = pz * fminf(fmaxf(px*rz, -limx), limx);
        float tyc = pz * fminf(fmaxf(py*rz, -limy), limy);

        float v00 = R00*c00 + R01*c01 + R02*c02;
        float v01 = R00*c01 + R01*c11 + R02*c12;
        float v02 = R00*c02 + R01*c12 + R02*c22;
        float v10 = R10*c00 + R11*c01 + R12*c02;
        float v11 = R10*c01 + R11*c11 + R12*c12;
        float v12 = R10*c02 + R11*c12 + R12*c22;
        float v20 = R20*c00 + R21*c01 + R22*c02;
        float v21 = R20*c01 + R21*c11 + R22*c12;
        float v22 = R20*c02 + R21*c12 + R22*c22;
        float cc00 = v00*R00 + v01*R01 + v02*R02;
        float cc01 = v00*R10 + v01*R11 + v02*R12;
        float cc02 = v00*R20 + v01*R21 + v02*R22;
        float cc11 = v10*R10 + v11*R11 + v12*R12;
        float cc12 = v10*R20 + v11*R21 + v12*R22;
        float cc22 = v20*R20 + v21*R21 + v22*R22;

        float j00 = fx*rz, j02 = -fx*txc*rz*rz;
        float j11 = fy*rz, j12 = -fy*tyc*rz*rz;
        float a  = j00*j00*cc00 + 2.f*j00*j02*cc02 + j02*j02*cc22 + EPS2D;
        float bq = j00*j11*cc01 + j00*j12*cc02 + j02*j11*cc12 + j02*j12*cc22;
        float d  = j11*j11*cc11 + 2.f*j11*j12*cc12 + j12*j12*cc22 + EPS2D;
        float det = a*d - bq*bq;

        if (!((pz > 0.01f) && (pz < 100.f) && (det > 0.f))) return false;

        float o = opac[g];
        float tau = __logf(255.f * o);
        if (!(tau > 0.f)) return false;

        // exact support bbox of {alpha > 1/255} = {sigma <= tau}:
        // half-extents sqrt(2*tau*Sigma'_00), sqrt(2*tau*Sigma'_11) (+margin)
        float hx = sqrtf(2.f*tau*a) + 0.02f;
        float hy = sqrtf(2.f*tau*d) + 0.02f;
        float uu = fx*px*rz + cx;
        float vv = fy*py*rz + cy;
        float xlo = (float)(TX*8) + 0.5f, xhi = (float)(TX*8) + 7.5f;
        float ylo = (float)(TY*8) + 0.5f, yhi = (float)(TY*8) + 7.5f;
        if (uu + hx < xlo || uu - hx > xhi || vv + hy < ylo || vv - hy > yhi)
            return false;

        float idet = 1.f / det;
        A = make_float4(uu, vv, 0.5f*LOG2E*d*idet, -LOG2E*bq*idet);
        B = make_float4(0.5f*LOG2E*a*idet, o, rgb[g*3+0], rgb[g*3+1]);
        C = rgb[g*3+2];
        return true;
    };

    float4 A0, B0, A1, B1; float C0, C1;
    bool kp0 = prep(tid,       A0, B0, C0);
    bool kp1 = prep(tid + 256, A1, B1, C1);

    // order-preserving compaction: segment s = (half<<2)|wv, lane order = i order
    unsigned long long bal0 = __ballot(kp0);
    unsigned long long bal1 = __ballot(kp1);
    if (lane == 0) { cnt[wv] = __popcll(bal0); cnt[4 + wv] = __popcll(bal1); }
    __syncthreads();
    int base0 = 0, base1 = 0, n2 = 0;
    #pragma unroll
    for (int s = 0; s < 8; s++) {
        int cs = cnt[s];
        base0 += (s < wv)     ? cs : 0;
        base1 += (s < 4 + wv) ? cs : 0;
        n2 += cs;
    }
    unsigned long long lt = (1ull << lane) - 1ull;
    int d0 = base0 + __popcll(bal0 & lt);
    int d1 = base1 + __popcll(bal1 & lt);
    if (kp0) { sA[d0] = A0; sB[d0] = B0; sC[d0] = C0; }
    if (kp1) { sA[d1] = A1; sB[d1] = B1; sC[d1] = C1; }
    __syncthreads();

    // ---- phase 4: segmented composite (wave wv = depth segment wv) ----
    const float pxl = (float)(TX*8 + (lane & 7)) + 0.5f;
    const float pyl = (float)(TY*8 + (lane >> 3)) + 0.5f;
    int seglen = (n2 + 3) >> 2;
    int js = wv * seglen;
    int je = min(n2, js + seglen);

    float T = 1.f, cr = 0.f, cg = 0.f, cb = 0.f;
#define CBODY(J) do { \
        float4 ga = sA[J]; float4 gb = sB[J]; float bv = sC[J]; \
        float dx = ga.x - pxl, dy = ga.y - pyl; \
        float sg = ga.z*dx*dx + gb.x*dy*dy + ga.w*dx*dy; \
        float al = fminf(gb.y * exp2f(-sg), ALPHA_MAX); \
        al = (sg >= 0.f && al > ALPHA_MIN) ? al : 0.f; \
        float wgt = al * T; \
        cr += wgt * gb.z; cg += wgt * gb.w; cb += wgt * bv; \
        T -= al * T; \
    } while (0)

    int j = js;
    while (j + 16 <= je) {
        #pragma unroll 4
        for (int q = 0; q < 16; q++) { CBODY(j + q); }
        j += 16;
        if (__all(T < 1e-4f)) break;
    }
    for (; j < je; j++) { CBODY(j); }
#undef CBODY

    shu.part[wv][lane] = make_float4(cr, cg, cb, T);
    __syncthreads();

    if (tid < 64) {
        float4 c0 = shu.part[0][lane];
        float Cr = c0.x, Cg = c0.y, Cb = c0.z, Tp = c0.w;
        #pragma unroll
        for (int s = 1; s < 4; s++) {
            float4 cs = shu.part[s][lane];
            Cr += Tp * cs.x;
            Cg += Tp * cs.y;
            Cb += Tp * cs.z;
            Tp *= cs.w;
        }
        int p = (TY*8 + (lane >> 3)) * WW + TX*8 + (lane & 7);
        float* img = out + (size_t)cam * (HH*WW*3) + (size_t)p * 3;
        img[0] = Cr + Tp;           // bg = (1,1,1)
        img[1] = Cg + Tp;
        img[2] = Cb + Tp;
        out[(size_t)NC*HH*WW*3 + (size_t)cam*(HH*WW) + p] = 1.f - Tp;
    }
}

extern "C" void kernel_launch(void* const* d_in, const int* in_sizes, int n_in,
                              void* d_out, int out_size, void* d_ws, size_t ws_size,
                              hipStream_t stream) {
    const float* w2cs  = (const float*)d_in[0];
    const float* Ks    = (const float*)d_in[1];
    const float* xyz   = (const float*)d_in[2];
    const float* rgb   = (const float*)d_in[3];
    const float* opac  = (const float*)d_in[4];
    const float* scale = (const float*)d_in[5];
    const float* rot   = (const float*)d_in[6];
    float* out = (float*)d_out;

    fused_kernel<<<dim3(TILES_X, TILES_Y, NC), 256, 0, stream>>>(
        w2cs, Ks, xyz, rgb, opac, scale, rot, out);
}